// Round 20
// baseline (381.339 us; speedup 1.0000x reference)
//
#include <hip/hip_runtime.h>
#include <cstdint>

// ---- problem constants ----
constexpr int B_       = 8;
constexpr int NPG_     = 12500;
constexpr int KSEL_    = 64;
constexpr int TOTAL_N_ = 100000;
constexpr int TOTAL_E_ = 1600000;
constexpr int EPG_     = 200000;
constexpr int NKEY_    = 16384;
constexpr int OUT_ROW  = KSEL_ * (128 + 32);       // 10240
constexpr int NB_SCAN  = (TOTAL_N_ + 255) / 256;   // 391
constexpr int BPG_     = (EPG_ + 255) / 256;       // 782

// bucket geometry: 32 dst rows/tile, 4 rows/wave, key includes row r, 2 src tiles
constexpr int TROWS_   = 32;
constexpr int NT_DST   = 391;
constexpr int NT_SRC   = 2;
constexpr int SRC_TW   = 6250;                     // 1.6MB feat window
constexpr int LBKT_    = NT_DST * 8 * 4 * NT_SRC;  // 25024 buckets per graph
constexpr int LBH_     = LBKT_ / 2;                // 12512 (split LDS arrays)
constexpr int NBKT     = B_ * LBKT_;               // 200192
constexpr int NB_BSCAN = NBKT / 256;               // 782 exact

// histogram privatization: 32 blocks/graph -> 256 blocks = 1 per CU
constexpr int BLKG_    = 32;
constexpr int NHB_     = B_ * BLKG_;               // 256
constexpr int ESLICE_  = EPG_ / BLKG_;             // 6250

typedef float f2v __attribute__((ext_vector_type(2)));
typedef int   i2v __attribute__((ext_vector_type(2)));

__device__ __forceinline__ float lrelu(float v){ return v >= 0.f ? v : 0.01f * v; }
__device__ __forceinline__ int   rlanei(int x, int l){ return __builtin_amdgcn_readlane(x, l); }
__device__ __forceinline__ float rlanef(float x, int l){
  return __uint_as_float(__builtin_amdgcn_readlane((int)__float_as_uint(x), l));
}

// ---------------- edge bucket key: (g, dt, wave, row, srctile) ----------------
__device__ __forceinline__ void edge_key(int s, int d, int& key, int& pk){
  int g   = d / NPG_;
  int dlc = d - g * NPG_;
  int slc = s - g * NPG_;
  int dt  = dlc >> 5;
  int dl  = dlc & 31;              // = 4*w + r
  int st  = slc / SRC_TW;          // 0..1
  key = ((g * NT_DST + dt) * 32 + dl) * NT_SRC + st;
  pk  = slc;
}

// ---------------- LDS-privatized histograms (no global atomics) ----------------
__global__ __launch_bounds__(1024, 1)
void hist_priv(const int* __restrict__ src, const int* __restrict__ dst,
               unsigned short* __restrict__ out_part,   // [NHB_][NPG_]
               unsigned short* __restrict__ bkt_part,   // [NHB_][LBKT_]
               unsigned short* __restrict__ lrank){     // [TOTAL_E_]
  __shared__ int oh [NPG_];   // 50000 B
  __shared__ int bhA[LBH_];   // 50048 B
  __shared__ int bhB[LBH_];   // 50048 B  (total ~147KB, 1 block/CU)
  int t  = threadIdx.x;
  int hb = blockIdx.x;
  int g  = hb & 7, sb = hb >> 3;
  for (int i = t; i < NPG_; i += 1024) oh[i] = 0;
  for (int i = t; i < LBH_; i += 1024){ bhA[i] = 0; bhB[i] = 0; }
  __syncthreads();
  int ebase = g * EPG_ + sb * ESLICE_;
  for (int i = t; i < ESLICE_; i += 1024){
    int e = ebase + i;
    int s = src[e], d = dst[e];
    atomicAdd(&oh[s - g * NPG_], 1);               // native ds_add
    int key, pk; edge_key(s, d, key, pk);
    int lk = key - g * LBKT_;
    int r = (lk < LBH_) ? atomicAdd(&bhA[lk], 1) : atomicAdd(&bhB[lk - LBH_], 1);
    lrank[e] = (unsigned short)r;
  }
  __syncthreads();
  unsigned short* op = out_part + (size_t)hb * NPG_;
  unsigned short* bp = bkt_part + (size_t)hb * LBKT_;
  for (int i = t; i < NPG_; i += 1024) op[i] = (unsigned short)oh[i];
  for (int i = t; i < LBH_; i += 1024){
    bp[i] = (unsigned short)bhA[i];
    bp[LBH_ + i] = (unsigned short)bhB[i];
  }
}

__global__ void hist_reduce_nodes(const unsigned short* __restrict__ out_part,
                                  float* __restrict__ rsq_out){
  int i = blockIdx.x * 256 + threadIdx.x;
  if (i < TOTAL_N_){
    int g = i / NPG_, nl = i - g * NPG_;
    int s = 0;
    #pragma unroll
    for (int sb = 0; sb < BLKG_; ++sb) s += (int)out_part[(size_t)(sb * 8 + g) * NPG_ + nl];
    if (s < 1) s = 1;
    rsq_out[i] = rsqrtf((float)s);
  }
}

__global__ void hist_reduce_bkt(unsigned short* __restrict__ bkt_part, int* __restrict__ bcnt){
  int k = blockIdx.x * 256 + threadIdx.x;
  if (k < NBKT){
    int g = k / LBKT_, lk = k - g * LBKT_;
    int run = 0;
    #pragma unroll
    for (int sb = 0; sb < BLKG_; ++sb){
      size_t idx = (size_t)(sb * 8 + g) * LBKT_ + lk;
      int v = (int)bkt_part[idx];
      bkt_part[idx] = (unsigned short)run;
      run += v;
    }
    bcnt[k] = run;
  }
}

// ---------------- generic exclusive scan ----------------
__global__ void scan_blocks(const int* __restrict__ cnt, int* __restrict__ off,
                            int* __restrict__ bsum, int n){
  __shared__ int tmp[256];
  int t = threadIdx.x;
  int i = blockIdx.x * 256 + t;
  int x = (i < n) ? cnt[i] : 0;
  tmp[t] = x;
  __syncthreads();
  for (int d = 1; d < 256; d <<= 1){
    int v = (t >= d) ? tmp[t - d] : 0;
    __syncthreads();
    tmp[t] += v;
    __syncthreads();
  }
  if (i < n) off[i] = tmp[t] - x;
  if (t == 255) bsum[blockIdx.x] = tmp[255];
}

__global__ void scan_sums(int* __restrict__ bsum, int nb){
  __shared__ int tmp[1024];
  int t = threadIdx.x;
  int x = (t < nb) ? bsum[t] : 0;
  tmp[t] = x;
  __syncthreads();
  for (int d = 1; d < 1024; d <<= 1){
    int v = (t >= d) ? tmp[t - d] : 0;
    __syncthreads();
    tmp[t] += v;
    __syncthreads();
  }
  if (t < nb) bsum[t] = tmp[t] - x;
}

__global__ void scan_add(int* __restrict__ off, const int* __restrict__ bsum, int n){
  int i = blockIdx.x * 256 + threadIdx.x;
  if (i < n) off[i] += bsum[blockIdx.x];
}

// ---------------- atomic-free bucket fill ----------------
__global__ void bfill2(const int* __restrict__ src, const int* __restrict__ dst,
                       const float* __restrict__ ew, const float* __restrict__ rsq_out,
                       const unsigned short* __restrict__ lrank,
                       const unsigned short* __restrict__ bkt_part, const int* __restrict__ boff,
                       i2v* __restrict__ bkt){
  int g  = blockIdx.x & 7;
  int il = (blockIdx.x >> 3) * 256 + threadIdx.x;
  if (il < EPG_){
    int e = g * EPG_ + il;
    int s = src[e], d = dst[e];
    int key, pk; edge_key(s, d, key, pk);
    int lk = key - g * LBKT_;
    int sb = il / ESLICE_;
    int slot = boff[key] + (int)bkt_part[(size_t)(sb * 8 + g) * LBKT_ + lk] + (int)lrank[e];
    i2v v; v.x = pk; v.y = __float_as_int(ew[e] * rsq_out[s]);
    bkt[slot] = v;
  }
}

// ---------------- layer 1: per-row-segment SpMM + W1 projection + stats ----------------
// Edge batches staged to LDS (uniform ds_read per edge, no readlane). W1 load deferred.
__global__ __launch_bounds__(512, 4)
void spmm1_tile(const int* __restrict__ boff, const i2v* __restrict__ bkt,
                const float* __restrict__ feat, const float* __restrict__ W1,
                float* __restrict__ h1, float* __restrict__ gsum, float* __restrict__ gsq){
  __shared__ float wsh[64 * 128];   // 32 KB: edge stage first, then W1
  __shared__ float sred[4][512];    // 8 KB — a-stage, then stats buffer
  int t = threadIdx.x;
  int w = t >> 6, lane = t & 63;
  int g = blockIdx.x & 7, dt = blockIdx.x >> 3;

  int wk = ((g * NT_DST + dt) * 32 + w * 4) * NT_SRC;   // wave's first bucket
  const float* fg = feat + (size_t)g * NPG_ * 64;

  // hoisted segment bounds (5 independent loads)
  int b0v = boff[wk];
  int b1v = boff[wk + NT_SRC];
  int b2v = boff[wk + 2 * NT_SRC];
  int b3v = boff[wk + 3 * NT_SRC];
  int nx  = wk + 4 * NT_SRC;
  int b4v = (nx < NBKT) ? boff[nx] : TOTAL_E_;
  int c0 = b1v - b0v, c1 = b2v - b1v, c2 = b3v - b2v, c3 = b4v - b3v;

  // hoisted batch loads: 4 vmem chains in flight
  i2v ev0 = {0,0}, ev1 = {0,0}, ev2 = {0,0}, ev3 = {0,0};
  if (lane < (c0 < 64 ? c0 : 64)) ev0 = bkt[b0v + lane];
  if (lane < (c1 < 64 ? c1 : 64)) ev1 = bkt[b1v + lane];
  if (lane < (c2 < 64 ? c2 : 64)) ev2 = bkt[b2v + lane];
  if (lane < (c3 < 64 ? c3 : 64)) ev3 = bkt[b3v + lane];

  // stage into wave-private LDS slice of wsh (same-wave write->read, program-ordered)
  i2v* est = ((i2v*)wsh) + w * 256;
  est[lane]       = ev0;
  est[64  + lane] = ev1;
  est[128 + lane] = ev2;
  est[192 + lane] = ev3;

  float a0, a1, a2, a3;

#define SEGP(R, BASE, CNT, ACC) {                                            \
    int m_ = (CNT) < 64 ? (CNT) : 64;                                        \
    float accA = 0.f, accB = 0.f, accC = 0.f, accD = 0.f;                    \
    int j = 0;                                                               \
    for (; j + 8 <= m_; j += 8){                                             \
      i2v e0 = est[R * 64 + j + 0];                                          \
      i2v e1 = est[R * 64 + j + 1];                                          \
      i2v e2 = est[R * 64 + j + 2];                                          \
      i2v e3 = est[R * 64 + j + 3];                                          \
      i2v e4 = est[R * 64 + j + 4];                                          \
      i2v e5 = est[R * 64 + j + 5];                                          \
      i2v e6 = est[R * 64 + j + 6];                                          \
      i2v e7 = est[R * 64 + j + 7];                                          \
      float f0 = fg[(size_t)e0.x * 64 + lane];                               \
      float f1 = fg[(size_t)e1.x * 64 + lane];                               \
      float f2 = fg[(size_t)e2.x * 64 + lane];                               \
      float f3 = fg[(size_t)e3.x * 64 + lane];                               \
      float f4 = fg[(size_t)e4.x * 64 + lane];                               \
      float f5 = fg[(size_t)e5.x * 64 + lane];                               \
      float f6 = fg[(size_t)e6.x * 64 + lane];                               \
      float f7 = fg[(size_t)e7.x * 64 + lane];                               \
      accA = fmaf(__int_as_float(e0.y), f0, accA);                           \
      accB = fmaf(__int_as_float(e1.y), f1, accB);                           \
      accC = fmaf(__int_as_float(e2.y), f2, accC);                           \
      accD = fmaf(__int_as_float(e3.y), f3, accD);                           \
      accA = fmaf(__int_as_float(e4.y), f4, accA);                           \
      accB = fmaf(__int_as_float(e5.y), f5, accB);                           \
      accC = fmaf(__int_as_float(e6.y), f6, accC);                           \
      accD = fmaf(__int_as_float(e7.y), f7, accD);                           \
    }                                                                        \
    for (; j < m_; ++j){                                                     \
      i2v ee = est[R * 64 + j];                                              \
      accA = fmaf(__int_as_float(ee.y), fg[(size_t)ee.x * 64 + lane], accA); \
    }                                                                        \
    for (int e2i = (BASE) + 64; e2i < (BASE) + (CNT); ++e2i){                \
      i2v ed = bkt[e2i];                                                     \
      accA = fmaf(__int_as_float(ed.y), fg[(size_t)ed.x * 64 + lane], accA); \
    }                                                                        \
    ACC = (accA + accB) + (accC + accD); }

  SEGP(0, b0v, c0, a0);
  SEGP(1, b1v, c1, a1);
  SEGP(2, b2v, c2, a2);
  SEGP(3, b3v, c3, a3);
#undef SEGP

  __syncthreads();   // all waves done reading est before W1 overwrites wsh
  for (int i = t; i < 64 * 128; i += 512) wsh[i] = W1[i];
  // stage aggregates into wave-private LDS slots (sred[r][w*64+lane])
  sred[0][t] = a0; sred[1][t] = a1; sred[2][t] = a2; sred[3][t] = a3;
  __syncthreads();   // W1 ready + stage visible

  // projection: b0..b3 via uniform LDS broadcast reads
  int rows = NPG_ - dt * TROWS_; if (rows > TROWS_) rows = TROWS_;
  const f2v* wp = (const f2v*)wsh;
  const int wb = w * 64;
  f2v A0 = {0.f,0.f}, A1 = {0.f,0.f}, A2 = {0.f,0.f}, A3 = {0.f,0.f};
  #pragma unroll 1
  for (int k = 0; k < 64; ++k){
    f2v wv = wp[k * 64 + lane];
    float b0 = sred[0][wb + k];
    float b1 = sred[1][wb + k];
    float b2 = sred[2][wb + k];
    float b3 = sred[3][wb + k];
    A0.x = fmaf(b0, wv.x, A0.x); A0.y = fmaf(b0, wv.y, A0.y);
    A1.x = fmaf(b1, wv.x, A1.x); A1.y = fmaf(b1, wv.y, A1.y);
    A2.x = fmaf(b2, wv.x, A2.x); A2.y = fmaf(b2, wv.y, A2.y);
    A3.x = fmaf(b3, wv.x, A3.x); A3.y = fmaf(b3, wv.y, A3.y);
  }
  float s0 = 0.f, q0 = 0.f, s1 = 0.f, q1 = 0.f;
  #pragma unroll
  for (int r = 0; r < 4; ++r){
    int lr = w * 4 + r;
    if (lr < rows){
      f2v A = (r == 0) ? A0 : (r == 1) ? A1 : (r == 2) ? A2 : A3;
      int cr = (r == 0) ? c0 : (r == 1) ? c1 : (r == 2) ? c2 : c3;
      float ri = rsqrtf((float)(cr < 1 ? 1 : cr));
      int node = g * NPG_ + dt * TROWS_ + lr;
      A.x *= ri; A.y *= ri;
      __builtin_nontemporal_store(A, (f2v*)&h1[(size_t)node * 128 + 2 * lane]);
      s0 += A.x; q0 = fmaf(A.x, A.x, q0);
      s1 += A.y; q1 = fmaf(A.y, A.y, q1);
    }
  }
  __syncthreads();   // all waves done reading stage before overwrite
  sred[0][t] = s0; sred[1][t] = q0; sred[2][t] = s1; sred[3][t] = q1;
  __syncthreads();
  if (t < 64){
    float S0 = 0.f, Q0 = 0.f, S1 = 0.f, Q1 = 0.f;
    #pragma unroll
    for (int ww = 0; ww < 8; ++ww){
      S0 += sred[0][t + 64*ww]; Q0 += sred[1][t + 64*ww];
      S1 += sred[2][t + 64*ww]; Q1 += sred[3][t + 64*ww];
    }
    atomicAdd(&gsum[g * 128 + 2*t],     S0);
    atomicAdd(&gsq [g * 128 + 2*t],     Q0);
    atomicAdd(&gsum[g * 128 + 2*t + 1], S1);
    atomicAdd(&gsq [g * 128 + 2*t + 1], Q1);
  }
}

__global__ void finalize1(const float* __restrict__ gsum, const float* __restrict__ gsq,
                          const float* __restrict__ gamma, const float* __restrict__ beta,
                          const float* __restrict__ alpha, float* __restrict__ mul, float* __restrict__ add){
  int i = threadIdx.x;            // 1024
  int c = i & 127;
  const float invn = 1.0f / (float)NPG_;
  float m = gsum[i] * invn;
  float a = alpha[c];
  float var = gsq[i] * invn - 2.f * a * m * m + a * a * m * m;
  float mu = gamma[c] * rsqrtf(var + 1e-5f);
  mul[i] = mu;
  add[i] = beta[c] - mu * a * m;
}

// ---------------- fused: normalize h1 + sort keys + project to h2p ----------------
__global__ __launch_bounds__(256, 4)
void normproj(const float* __restrict__ h1,
              const float* __restrict__ mul, const float* __restrict__ add,
              const float* __restrict__ W2,
              unsigned long long* __restrict__ keys, float* __restrict__ h2p){
  __shared__ float w2s[128 * 32];  // 16 KB
  __shared__ float ys[4][128];     // 2 KB, wave-private rows
  int t = threadIdx.x;
  for (int i = t; i < 128 * 32; i += 256) w2s[i] = W2[i];
  __syncthreads();

  int g     = blockIdx.x & 7;
  int wslot = (blockIdx.x >> 3) * 4 + (t >> 6);   // 0..1023
  int w     = t >> 6;
  int lane  = t & 63;
  int c     = lane & 31, hh = lane >> 5;
  int kb    = hh * 64;

  float m0 = mul[g * 128 + lane],      aa0 = add[g * 128 + lane];
  float m1 = mul[g * 128 + 64 + lane], aa1 = add[g * 128 + 64 + lane];

  int nv = (NPG_ - wslot + 1023) / 1024;

  int v0 = g * NPG_ + wslot;
  float x0 = __builtin_nontemporal_load(&h1[(size_t)v0 * 128 + lane]);
  float x1 = __builtin_nontemporal_load(&h1[(size_t)v0 * 128 + 64 + lane]);

  for (int i = 0; i < nv; ++i){
    int v = g * NPG_ + wslot + i * 1024;
    float cur0 = x0, cur1 = x1;
    if (i + 1 < nv){
      int vn = v + 1024;
      x0 = __builtin_nontemporal_load(&h1[(size_t)vn * 128 + lane]);
      x1 = __builtin_nontemporal_load(&h1[(size_t)vn * 128 + 64 + lane]);
    }
    float y0 = lrelu(fmaf(m0, cur0, aa0));
    float y1 = lrelu(fmaf(m1, cur1, aa1));
    ys[w][lane]      = y0;
    ys[w][64 + lane] = y1;
    float mx = fmaxf(y0, y1);
    for (int o = 1; o < 64; o <<= 1) mx = fmaxf(mx, __shfl_xor(mx, o));
    if (lane == 0){
      unsigned u = __float_as_uint(mx);
      u ^= (u >> 31) ? 0xFFFFFFFFu : 0x80000000u;
      int nloc = v - g * NPG_;
      keys[(size_t)g * NKEY_ + nloc] = ((unsigned long long)(~u) << 32) | (unsigned)nloc;
    }
    float ac0 = 0.f, ac1 = 0.f, ac2 = 0.f, ac3 = 0.f;
    #pragma unroll
    for (int kk = 0; kk < 16; ++kk){
      ac0 = fmaf(ys[w][kb + kk],      w2s[(kb + kk) * 32 + c],      ac0);
      ac1 = fmaf(ys[w][kb + kk + 16], w2s[(kb + kk + 16) * 32 + c], ac1);
      ac2 = fmaf(ys[w][kb + kk + 32], w2s[(kb + kk + 32) * 32 + c], ac2);
      ac3 = fmaf(ys[w][kb + kk + 48], w2s[(kb + kk + 48) * 32 + c], ac3);
    }
    float acc = (ac0 + ac1) + (ac2 + ac3);
    acc += __shfl_xor(acc, 32);
    if (hh == 0) h2p[(size_t)v * 32 + c] = acc;
  }
}

// ---------------- top-k selection (2-stage bitonic) ----------------
__global__ void topk_s1(const unsigned long long* __restrict__ keys, unsigned long long* __restrict__ cand){
  __shared__ unsigned long long s[2048];
  int b = blockIdx.x >> 3, ch = blockIdx.x & 7;
  int t = threadIdx.x;            // 256
  for (int i = t; i < 2048; i += 256) s[i] = keys[(size_t)b * NKEY_ + (size_t)ch * 2048 + i];
  for (int k2 = 2; k2 <= 2048; k2 <<= 1){
    for (int j = k2 >> 1; j > 0; j >>= 1){
      __syncthreads();
      for (int i = t; i < 2048; i += 256){
        int p = i ^ j;
        if (p > i){
          unsigned long long A = s[i], C = s[p];
          bool up = ((i & k2) == 0);
          if ((A > C) == up){ s[i] = C; s[p] = A; }
        }
      }
    }
  }
  __syncthreads();
  if (t < 64) cand[(size_t)b * 512 + (size_t)ch * 64 + t] = s[t];
}

__global__ void topk_s2(const unsigned long long* __restrict__ cand, int* __restrict__ topidx){
  __shared__ unsigned long long s[512];
  int b = blockIdx.x;
  int t = threadIdx.x;            // 256
  for (int i = t; i < 512; i += 256) s[i] = cand[(size_t)b * 512 + i];
  for (int k2 = 2; k2 <= 512; k2 <<= 1){
    for (int j = k2 >> 1; j > 0; j >>= 1){
      __syncthreads();
      for (int i = t; i < 512; i += 256){
        int p = i ^ j;
        if (p > i){
          unsigned long long A = s[i], C = s[p];
          bool up = ((i & k2) == 0);
          if ((A > C) == up){ s[i] = C; s[p] = A; }
        }
      }
    }
  }
  __syncthreads();
  if (t < 64) topidx[b * 64 + t] = (int)(s[t] & 0xFFFFFFFFull);
}

__global__ void emit1(const float* __restrict__ h1, const int* __restrict__ topidx,
                      const float* __restrict__ mul, const float* __restrict__ add,
                      float* __restrict__ out){
  __shared__ float s[128];
  int b = blockIdx.x >> 6, k = blockIdx.x & 63;
  int t = threadIdx.x;            // 128
  int nloc = topidx[b * 64 + k];
  float raw = h1[((size_t)b * NPG_ + nloc) * 128 + t];
  s[t] = lrelu(fmaf(mul[b * 128 + t], raw, add[b * 128 + t]));
  for (int k2 = 2; k2 <= 128; k2 <<= 1){
    for (int j = k2 >> 1; j > 0; j >>= 1){
      __syncthreads();
      int p = t ^ j;
      if (p > t){
        float A = s[t], C = s[p];
        bool up = ((t & k2) == 0);
        if ((A > C) == up){ s[t] = C; s[p] = A; }
      }
    }
  }
  __syncthreads();
  out[(size_t)b * OUT_ROW + (size_t)k * 128 + t] = lrelu(s[t]);
}

// ---------------- layer 2: per-row-segment SpMM on h2p + stats ----------------
// Edge batches staged to LDS (uniform ds_read per edge, no readlane).
__global__ __launch_bounds__(512, 4)
void spmm2_tile(const int* __restrict__ boff, const i2v* __restrict__ bkt,
                const float* __restrict__ h2p, float* __restrict__ h2c,
                float* __restrict__ gsum, float* __restrict__ gsq){
  __shared__ float sred[2][512];   // 4 KB
  __shared__ i2v   est2[8][256];   // 16 KB edge stage (wave-private rows)
  int t = threadIdx.x;
  int w = t >> 6, lane = t & 63;
  int c = lane & 31, h = lane >> 5;
  int g = blockIdx.x & 7, dt = blockIdx.x >> 3;

  int wk = ((g * NT_DST + dt) * 32 + w * 4) * NT_SRC;
  const float* hg = h2p + (size_t)g * NPG_ * 32;
  int rows = NPG_ - dt * TROWS_; if (rows > TROWS_) rows = TROWS_;

  // hoisted segment bounds
  int b0v = boff[wk];
  int b1v = boff[wk + NT_SRC];
  int b2v = boff[wk + 2 * NT_SRC];
  int b3v = boff[wk + 3 * NT_SRC];
  int nx  = wk + 4 * NT_SRC;
  int b4v = (nx < NBKT) ? boff[nx] : TOTAL_E_;
  int c0 = b1v - b0v, c1 = b2v - b1v, c2 = b3v - b2v, c3 = b4v - b3v;

  // hoisted batch loads
  i2v ev0 = {0,0}, ev1 = {0,0}, ev2 = {0,0}, ev3 = {0,0};
  if (lane < (c0 < 64 ? c0 : 64)) ev0 = bkt[b0v + lane];
  if (lane < (c1 < 64 ? c1 : 64)) ev1 = bkt[b1v + lane];
  if (lane < (c2 < 64 ? c2 : 64)) ev2 = bkt[b2v + lane];
  if (lane < (c3 < 64 ? c3 : 64)) ev3 = bkt[b3v + lane];

  // stage to wave-private LDS (program-ordered within wave)
  est2[w][lane]       = ev0;
  est2[w][64  + lane] = ev1;
  est2[w][128 + lane] = ev2;
  est2[w][192 + lane] = ev3;

  float A0, A1, A2, A3;

#define SEGP2(R, BASE, CNT, ACC) {                                           \
    int m_ = (CNT) < 64 ? (CNT) : 64;                                        \
    float ac0 = 0.f, ac1 = 0.f;                                              \
    int j = 0;                                                               \
    for (; j + 4 <= m_; j += 4){                                             \
      i2v eA0 = est2[w][R * 64 + j + 0];                                     \
      i2v eB0 = est2[w][R * 64 + j + 1];                                     \
      i2v eA1 = est2[w][R * 64 + j + 2];                                     \
      i2v eB1 = est2[w][R * 64 + j + 3];                                     \
      int   p0 = h ? eB0.x : eA0.x;                                          \
      float q0 = __int_as_float(h ? eB0.y : eA0.y);                          \
      int   p1 = h ? eB1.x : eA1.x;                                          \
      float q1 = __int_as_float(h ? eB1.y : eA1.y);                          \
      float f0 = hg[(size_t)p0 * 32 + c];                                    \
      float f1 = hg[(size_t)p1 * 32 + c];                                    \
      ac0 = fmaf(q0, f0, ac0); ac1 = fmaf(q1, f1, ac1);                      \
    }                                                                        \
    for (; j + 2 <= m_; j += 2){                                             \
      i2v eA = est2[w][R * 64 + j];                                          \
      i2v eB = est2[w][R * 64 + j + 1];                                      \
      int   p = h ? eB.x : eA.x;                                             \
      float q = __int_as_float(h ? eB.y : eA.y);                             \
      ac0 = fmaf(q, hg[(size_t)p * 32 + c], ac0);                            \
    }                                                                        \
    if (j < m_){                                                             \
      i2v eA = est2[w][R * 64 + j];                                          \
      float q = h ? 0.f : __int_as_float(eA.y);                              \
      ac0 = fmaf(q, hg[(size_t)eA.x * 32 + c], ac0);                         \
    }                                                                        \
    for (int e2i = (BASE) + 64; e2i < (BASE) + (CNT); ++e2i){                \
      i2v ed = bkt[e2i];                                                     \
      float q = h ? 0.f : __int_as_float(ed.y);                              \
      ac0 = fmaf(q, hg[(size_t)ed.x * 32 + c], ac0);                         \
    }                                                                        \
    float acc_ = ac0 + ac1;                                                  \
    acc_ += __shfl_xor(acc_, 32);                                            \
    ACC = acc_; }

  SEGP2(0, b0v, c0, A0);
  SEGP2(1, b1v, c1, A1);
  SEGP2(2, b2v, c2, A2);
  SEGP2(3, b3v, c3, A3);
#undef SEGP2

  float ssum = 0.f, ssq = 0.f;
  #pragma unroll
  for (int r = 0; r < 4; ++r){
    float acc = (r == 0) ? A0 : (r == 1) ? A1 : (r == 2) ? A2 : A3;
    int   cr  = (r == 0) ? c0 : (r == 1) ? c1 : (r == 2) ? c2 : c3;
    int lr = w * 4 + r;
    if (lr < rows && h == 0){
      float ri = rsqrtf((float)(cr < 1 ? 1 : cr));
      float val = acc * ri;
      int node = g * NPG_ + dt * TROWS_ + lr;
      __builtin_nontemporal_store(val, &h2c[(size_t)node * 32 + c]);
      ssum += val; ssq = fmaf(val, val, ssq);
    }
  }

  __syncthreads();
  sred[0][t] = ssum; sred[1][t] = ssq;
  __syncthreads();
  if (t < 32){
    float S = 0.f, Q = 0.f;
    #pragma unroll
    for (int k = 0; k < 16; ++k){
      S += sred[0][t + 32 * k];
      Q += sred[1][t + 32 * k];
    }
    atomicAdd(&gsum[g * 32 + t], S);
    atomicAdd(&gsq [g * 32 + t], Q);
  }
}

__global__ void finalize2(const float* __restrict__ gsum, const float* __restrict__ gsq,
                          const float* __restrict__ gamma, const float* __restrict__ beta,
                          const float* __restrict__ alpha, float* __restrict__ mul, float* __restrict__ add){
  int i = threadIdx.x;            // 256
  int c = i & 31;
  const float invn = 1.0f / (float)NPG_;
  float m = gsum[i] * invn;
  float a = alpha[c];
  float var = gsq[i] * invn - 2.f * a * m * m + a * a * m * m;
  float mu = gamma[c] * rsqrtf(var + 1e-5f);
  mul[i] = mu;
  add[i] = beta[c] - mu * a * m;
}

__global__ void norm2(float* __restrict__ h, const float* __restrict__ mul, const float* __restrict__ add,
                      unsigned long long* __restrict__ keys){
  int tid  = blockIdx.x * 256 + threadIdx.x;
  int node = tid >> 5;
  int sl   = tid & 31;
  if (node >= TOTAL_N_) return;
  int b = node / NPG_;
  int nloc = node - b * NPG_;
  float v = h[(size_t)node * 32 + sl];
  v = lrelu(fmaf(mul[b * 32 + sl], v, add[b * 32 + sl]));
  h[(size_t)node * 32 + sl] = v;
  float m = v;
  for (int o = 1; o < 32; o <<= 1) m = fmaxf(m, __shfl_xor(m, o));
  if (sl == 0){
    unsigned u = __float_as_uint(m);
    u ^= (u >> 31) ? 0xFFFFFFFFu : 0x80000000u;
    keys[(size_t)b * NKEY_ + nloc] = ((unsigned long long)(~u) << 32) | (unsigned)nloc;
  }
}

__global__ void emit2(const float* __restrict__ h2, const int* __restrict__ topidx, float* __restrict__ out){
  int b = blockIdx.x >> 6, k = blockIdx.x & 63;
  int lane = threadIdx.x;         // 32
  int nloc = topidx[b * 64 + k];
  float v = h2[((size_t)b * NPG_ + nloc) * 32 + lane];
  for (int k2 = 2; k2 <= 32; k2 <<= 1){
    for (int j = k2 >> 1; j > 0; j >>= 1){
      float o = __shfl_xor(v, j);
      bool up    = ((lane & k2) == 0);
      bool lower = ((lane & j) == 0);
      v = (up == lower) ? fminf(v, o) : fmaxf(v, o);
    }
  }
  out[(size_t)b * OUT_ROW + 8192 + (size_t)k * 32 + lane] = lrelu(v);
}

__global__ void sentinel_kernel(float* out){
  int i = blockIdx.x * 256 + threadIdx.x;
  if (i < B_ * OUT_ROW) out[i] = -777.0f;
}

extern "C" void kernel_launch(void* const* d_in, const int* in_sizes, int n_in,
                              void* d_out, int out_size, void* d_ws, size_t ws_size,
                              hipStream_t stream){
  const float* feat   = (const float*)d_in[0];
  const float* ew     = (const float*)d_in[1];
  const float* W1     = (const float*)d_in[2];
  const float* W2     = (const float*)d_in[3];
  const float* gamma1 = (const float*)d_in[4];
  const float* beta1  = (const float*)d_in[5];
  const float* alpha1 = (const float*)d_in[6];
  const float* gamma2 = (const float*)d_in[7];
  const float* beta2  = (const float*)d_in[8];
  const float* alpha2 = (const float*)d_in[9];
  const int*   esrc   = (const int*)d_in[10];
  const int*   edst   = (const int*)d_in[11];
  float* out = (float*)d_out;

  char* ws = (char*)d_ws;
  auto alloc = [&](size_t bytes) -> char* {
    char* p = ws;
    ws += (bytes + 255) & ~(size_t)255;
    return p;
  };

  // zeroed region (must stay first & contiguous)
  float* gsum1   = (float*)alloc(1024 * 4);
  float* gsq1    = (float*)alloc(1024 * 4);
  float* gsum2   = (float*)alloc(256 * 4);
  float* gsq2    = (float*)alloc(256 * 4);
  size_t zero_bytes = (size_t)(ws - (char*)d_ws);

  float* rsq_out = (float*)alloc((size_t)TOTAL_N_ * 4);
  unsigned short* out_part = (unsigned short*)alloc((size_t)NHB_ * NPG_ * 2);   // 6.4 MB
  unsigned short* bkt_part = (unsigned short*)alloc((size_t)NHB_ * LBKT_ * 2);  // 12.8 MB
  unsigned short* lrank = (unsigned short*)alloc((size_t)TOTAL_E_ * 2);         // 3.2 MB
  int*   bcnt    = (int*)  alloc((size_t)NBKT * 4);
  int*   boff    = (int*)  alloc((size_t)NBKT * 4);
  int*   bsum    = (int*)  alloc(1024 * 4);
  float* mul1    = (float*)alloc(1024 * 4);
  float* add1    = (float*)alloc(1024 * 4);
  float* mul2    = (float*)alloc(256 * 4);
  float* add2    = (float*)alloc(256 * 4);
  int*   topidx1 = (int*)  alloc(512 * 4);
  int*   topidx2 = (int*)  alloc(512 * 4);
  unsigned long long* cand = (unsigned long long*)alloc((size_t)B_ * 512 * 8);
  unsigned long long* keys = (unsigned long long*)alloc((size_t)B_ * NKEY_ * 8);
  i2v*   bkt     = (i2v*)  alloc((size_t)TOTAL_E_ * 8);
  float* h2p     = (float*)alloc((size_t)TOTAL_N_ * 32 * 4);
  float* h2c     = (float*)alloc((size_t)TOTAL_N_ * 32 * 4);
  float* h1      = (float*)alloc((size_t)TOTAL_N_ * 128 * 4);

  size_t need = (size_t)(ws - (char*)d_ws);
  if (need > ws_size){
    sentinel_kernel<<<(B_ * OUT_ROW + 255) / 256, 256, 0, stream>>>(out);
    return;
  }

  hipMemsetAsync(d_ws, 0, zero_bytes, stream);
  hipMemsetAsync(keys, 0xFF, (size_t)B_ * NKEY_ * 8, stream);

  hist_priv        <<<NHB_, 1024, 0, stream>>>(esrc, edst, out_part, bkt_part, lrank);
  hist_reduce_nodes<<<NB_SCAN, 256, 0, stream>>>(out_part, rsq_out);
  hist_reduce_bkt  <<<NB_BSCAN, 256, 0, stream>>>(bkt_part, bcnt);
  scan_blocks      <<<NB_BSCAN, 256, 0, stream>>>(bcnt, boff, bsum, NBKT);
  scan_sums        <<<1, 1024, 0, stream>>>(bsum, NB_BSCAN);
  scan_add         <<<NB_BSCAN, 256, 0, stream>>>(boff, bsum, NBKT);
  bfill2           <<<8 * BPG_, 256, 0, stream>>>(esrc, edst, ew, rsq_out, lrank,
                                                  bkt_part, boff, bkt);

  // layer 1
  spmm1_tile <<<NT_DST * 8, 512, 0, stream>>>(boff, bkt, feat, W1, h1, gsum1, gsq1);
  finalize1  <<<1, 1024, 0, stream>>>(gsum1, gsq1, gamma1, beta1, alpha1, mul1, add1);
  normproj   <<<2048, 256, 0, stream>>>(h1, mul1, add1, W2, keys, h2p);
  topk_s1    <<<B_ * 8, 256, 0, stream>>>(keys, cand);
  topk_s2    <<<B_, 256, 0, stream>>>(cand, topidx1);
  emit1      <<<B_ * 64, 128, 0, stream>>>(h1, topidx1, mul1, add1, out);

  // layer 2
  spmm2_tile <<<NT_DST * 8, 512, 0, stream>>>(boff, bkt, h2p, h2c, gsum2, gsq2);
  finalize2  <<<1, 256, 0, stream>>>(gsum2, gsq2, gamma2, beta2, alpha2, mul2, add2);
  norm2      <<<TOTAL_N_ * 32 / 256, 256, 0, stream>>>(h2c, mul2, add2, keys);
  topk_s1    <<<B_ * 8, 256, 0, stream>>>(keys, cand);
  topk_s2    <<<B_, 256, 0, stream>>>(cand, topidx2);
  emit2      <<<B_ * 64, 32, 0, stream>>>(h2c, topidx2, out);
}

// Round 21
// 378.858 us; speedup vs baseline: 1.0065x; 1.0065x over previous
//
#include <hip/hip_runtime.h>
#include <cstdint>

// ---- problem constants ----
constexpr int B_       = 8;
constexpr int NPG_     = 12500;
constexpr int KSEL_    = 64;
constexpr int TOTAL_N_ = 100000;
constexpr int TOTAL_E_ = 1600000;
constexpr int EPG_     = 200000;
constexpr int NKEY_    = 16384;
constexpr int OUT_ROW  = KSEL_ * (128 + 32);       // 10240
constexpr int NB_SCAN  = (TOTAL_N_ + 255) / 256;   // 391
constexpr int BPG_     = (EPG_ + 255) / 256;       // 782

// bucket geometry: 32 dst rows/tile, 4 rows/wave, key includes row r, 2 src tiles
constexpr int TROWS_   = 32;
constexpr int NT_DST   = 391;
constexpr int NT_SRC   = 2;
constexpr int SRC_TW   = 6250;                     // 1.6MB feat window
constexpr int LBKT_    = NT_DST * 8 * 4 * NT_SRC;  // 25024 buckets per graph
constexpr int LBH_     = LBKT_ / 2;                // 12512 (split LDS arrays)
constexpr int NBKT     = B_ * LBKT_;               // 200192
constexpr int NB_BSCAN = NBKT / 256;               // 782 exact

// histogram privatization: 32 blocks/graph -> 256 blocks = 1 per CU
constexpr int BLKG_    = 32;
constexpr int NHB_     = B_ * BLKG_;               // 256
constexpr int ESLICE_  = EPG_ / BLKG_;             // 6250

typedef float f2v __attribute__((ext_vector_type(2)));
typedef int   i2v __attribute__((ext_vector_type(2)));

__device__ __forceinline__ float lrelu(float v){ return v >= 0.f ? v : 0.01f * v; }
__device__ __forceinline__ int   rlanei(int x, int l){ return __builtin_amdgcn_readlane(x, l); }
__device__ __forceinline__ float rlanef(float x, int l){
  return __uint_as_float(__builtin_amdgcn_readlane((int)__float_as_uint(x), l));
}

// ---------------- edge bucket key: (g, dt, wave, row, srctile) ----------------
__device__ __forceinline__ void edge_key(int s, int d, int& key, int& pk){
  int g   = d / NPG_;
  int dlc = d - g * NPG_;
  int slc = s - g * NPG_;
  int dt  = dlc >> 5;
  int dl  = dlc & 31;              // = 4*w + r
  int st  = slc / SRC_TW;          // 0..1
  key = ((g * NT_DST + dt) * 32 + dl) * NT_SRC + st;
  pk  = slc;
}

// ---------------- LDS-privatized histograms (no global atomics) ----------------
__global__ __launch_bounds__(1024, 1)
void hist_priv(const int* __restrict__ src, const int* __restrict__ dst,
               unsigned short* __restrict__ out_part,   // [NHB_][NPG_]
               unsigned short* __restrict__ bkt_part,   // [NHB_][LBKT_]
               unsigned short* __restrict__ lrank){     // [TOTAL_E_]
  __shared__ int oh [NPG_];   // 50000 B
  __shared__ int bhA[LBH_];   // 50048 B
  __shared__ int bhB[LBH_];   // 50048 B  (total ~147KB, 1 block/CU)
  int t  = threadIdx.x;
  int hb = blockIdx.x;
  int g  = hb & 7, sb = hb >> 3;
  for (int i = t; i < NPG_; i += 1024) oh[i] = 0;
  for (int i = t; i < LBH_; i += 1024){ bhA[i] = 0; bhB[i] = 0; }
  __syncthreads();
  int ebase = g * EPG_ + sb * ESLICE_;
  for (int i = t; i < ESLICE_; i += 1024){
    int e = ebase + i;
    int s = src[e], d = dst[e];
    atomicAdd(&oh[s - g * NPG_], 1);               // native ds_add
    int key, pk; edge_key(s, d, key, pk);
    int lk = key - g * LBKT_;
    int r = (lk < LBH_) ? atomicAdd(&bhA[lk], 1) : atomicAdd(&bhB[lk - LBH_], 1);
    lrank[e] = (unsigned short)r;
  }
  __syncthreads();
  unsigned short* op = out_part + (size_t)hb * NPG_;
  unsigned short* bp = bkt_part + (size_t)hb * LBKT_;
  for (int i = t; i < NPG_; i += 1024) op[i] = (unsigned short)oh[i];
  for (int i = t; i < LBH_; i += 1024){
    bp[i] = (unsigned short)bhA[i];
    bp[LBH_ + i] = (unsigned short)bhB[i];
  }
}

__global__ void hist_reduce_nodes(const unsigned short* __restrict__ out_part,
                                  float* __restrict__ rsq_out){
  int i = blockIdx.x * 256 + threadIdx.x;
  if (i < TOTAL_N_){
    int g = i / NPG_, nl = i - g * NPG_;
    int s = 0;
    #pragma unroll
    for (int sb = 0; sb < BLKG_; ++sb) s += (int)out_part[(size_t)(sb * 8 + g) * NPG_ + nl];
    if (s < 1) s = 1;
    rsq_out[i] = rsqrtf((float)s);
  }
}

__global__ void hist_reduce_bkt(unsigned short* __restrict__ bkt_part, int* __restrict__ bcnt){
  int k = blockIdx.x * 256 + threadIdx.x;
  if (k < NBKT){
    int g = k / LBKT_, lk = k - g * LBKT_;
    int run = 0;
    #pragma unroll
    for (int sb = 0; sb < BLKG_; ++sb){
      size_t idx = (size_t)(sb * 8 + g) * LBKT_ + lk;
      int v = (int)bkt_part[idx];
      bkt_part[idx] = (unsigned short)run;
      run += v;
    }
    bcnt[k] = run;
  }
}

// ---------------- generic exclusive scan ----------------
__global__ void scan_blocks(const int* __restrict__ cnt, int* __restrict__ off,
                            int* __restrict__ bsum, int n){
  __shared__ int tmp[256];
  int t = threadIdx.x;
  int i = blockIdx.x * 256 + t;
  int x = (i < n) ? cnt[i] : 0;
  tmp[t] = x;
  __syncthreads();
  for (int d = 1; d < 256; d <<= 1){
    int v = (t >= d) ? tmp[t - d] : 0;
    __syncthreads();
    tmp[t] += v;
    __syncthreads();
  }
  if (i < n) off[i] = tmp[t] - x;
  if (t == 255) bsum[blockIdx.x] = tmp[255];
}

__global__ void scan_sums(int* __restrict__ bsum, int nb){
  __shared__ int tmp[1024];
  int t = threadIdx.x;
  int x = (t < nb) ? bsum[t] : 0;
  tmp[t] = x;
  __syncthreads();
  for (int d = 1; d < 1024; d <<= 1){
    int v = (t >= d) ? tmp[t - d] : 0;
    __syncthreads();
    tmp[t] += v;
    __syncthreads();
  }
  if (t < nb) bsum[t] = tmp[t] - x;
}

__global__ void scan_add(int* __restrict__ off, const int* __restrict__ bsum, int n){
  int i = blockIdx.x * 256 + threadIdx.x;
  if (i < n) off[i] += bsum[blockIdx.x];
}

// ---------------- atomic-free bucket fill ----------------
__global__ void bfill2(const int* __restrict__ src, const int* __restrict__ dst,
                       const float* __restrict__ ew, const float* __restrict__ rsq_out,
                       const unsigned short* __restrict__ lrank,
                       const unsigned short* __restrict__ bkt_part, const int* __restrict__ boff,
                       i2v* __restrict__ bkt){
  int g  = blockIdx.x & 7;
  int il = (blockIdx.x >> 3) * 256 + threadIdx.x;
  if (il < EPG_){
    int e = g * EPG_ + il;
    int s = src[e], d = dst[e];
    int key, pk; edge_key(s, d, key, pk);
    int lk = key - g * LBKT_;
    int sb = il / ESLICE_;
    int slot = boff[key] + (int)bkt_part[(size_t)(sb * 8 + g) * LBKT_ + lk] + (int)lrank[e];
    i2v v; v.x = pk; v.y = __float_as_int(ew[e] * rsq_out[s]);
    bkt[slot] = v;
  }
}

// ---------------- layer 1: per-row-segment SpMM + W1 projection + stats ----------------
// All 4 segments' bounds + batch loads hoisted (4 vmem chains in flight).
__global__ __launch_bounds__(512, 4)
void spmm1_tile(const int* __restrict__ boff, const i2v* __restrict__ bkt,
                const float* __restrict__ feat, const float* __restrict__ W1,
                float* __restrict__ h1, float* __restrict__ gsum, float* __restrict__ gsq){
  __shared__ float wsh[64 * 128];   // 32 KB
  __shared__ float sred[4][512];    // 8 KB — stage buffer, then stats buffer
  int t = threadIdx.x;
  int w = t >> 6, lane = t & 63;
  int g = blockIdx.x & 7, dt = blockIdx.x >> 3;

  for (int i = t; i < 64 * 128; i += 512) wsh[i] = W1[i];

  int wk = ((g * NT_DST + dt) * 32 + w * 4) * NT_SRC;   // wave's first bucket
  const float* fg = feat + (size_t)g * NPG_ * 64;

  // hoisted segment bounds (5 independent loads)
  int b0v = boff[wk];
  int b1v = boff[wk + NT_SRC];
  int b2v = boff[wk + 2 * NT_SRC];
  int b3v = boff[wk + 3 * NT_SRC];
  int nx  = wk + 4 * NT_SRC;
  int b4v = (nx < NBKT) ? boff[nx] : TOTAL_E_;
  int c0 = b1v - b0v, c1 = b2v - b1v, c2 = b3v - b2v, c3 = b4v - b3v;

  // hoisted batch loads: 4 vmem chains in flight
  i2v ev0 = {0,0}, ev1 = {0,0}, ev2 = {0,0}, ev3 = {0,0};
  if (lane < (c0 < 64 ? c0 : 64)) ev0 = bkt[b0v + lane];
  if (lane < (c1 < 64 ? c1 : 64)) ev1 = bkt[b1v + lane];
  if (lane < (c2 < 64 ? c2 : 64)) ev2 = bkt[b2v + lane];
  if (lane < (c3 < 64 ? c3 : 64)) ev3 = bkt[b3v + lane];

  float a0, a1, a2, a3;

#define SEGP(EV, BASE, CNT, ACC) {                                           \
    int m_ = (CNT) < 64 ? (CNT) : 64;                                        \
    float accA = 0.f, accB = 0.f, accC = 0.f, accD = 0.f;                    \
    int j = 0;                                                               \
    for (; j + 8 <= m_; j += 8){                                             \
      int   p0 = rlanei(EV.x, j+0), p1 = rlanei(EV.x, j+1);                  \
      int   p2 = rlanei(EV.x, j+2), p3 = rlanei(EV.x, j+3);                  \
      int   p4 = rlanei(EV.x, j+4), p5 = rlanei(EV.x, j+5);                  \
      int   p6 = rlanei(EV.x, j+6), p7 = rlanei(EV.x, j+7);                  \
      float q0 = rlanef(__int_as_float(EV.y), j+0), q1 = rlanef(__int_as_float(EV.y), j+1); \
      float q2 = rlanef(__int_as_float(EV.y), j+2), q3 = rlanef(__int_as_float(EV.y), j+3); \
      float q4 = rlanef(__int_as_float(EV.y), j+4), q5 = rlanef(__int_as_float(EV.y), j+5); \
      float q6 = rlanef(__int_as_float(EV.y), j+6), q7 = rlanef(__int_as_float(EV.y), j+7); \
      float f0 = fg[(size_t)p0 * 64 + lane];                                 \
      float f1 = fg[(size_t)p1 * 64 + lane];                                 \
      float f2 = fg[(size_t)p2 * 64 + lane];                                 \
      float f3 = fg[(size_t)p3 * 64 + lane];                                 \
      float f4 = fg[(size_t)p4 * 64 + lane];                                 \
      float f5 = fg[(size_t)p5 * 64 + lane];                                 \
      float f6 = fg[(size_t)p6 * 64 + lane];                                 \
      float f7 = fg[(size_t)p7 * 64 + lane];                                 \
      accA = fmaf(q0, f0, accA); accB = fmaf(q1, f1, accB);                  \
      accC = fmaf(q2, f2, accC); accD = fmaf(q3, f3, accD);                  \
      accA = fmaf(q4, f4, accA); accB = fmaf(q5, f5, accB);                  \
      accC = fmaf(q6, f6, accC); accD = fmaf(q7, f7, accD);                  \
    }                                                                        \
    for (; j < m_; ++j){                                                     \
      int p = rlanei(EV.x, j);                                               \
      float q = rlanef(__int_as_float(EV.y), j);                             \
      accA = fmaf(q, fg[(size_t)p * 64 + lane], accA);                       \
    }                                                                        \
    for (int e2 = (BASE) + 64; e2 < (BASE) + (CNT); ++e2){                   \
      i2v ed = bkt[e2];                                                      \
      accA = fmaf(__int_as_float(ed.y), fg[(size_t)ed.x * 64 + lane], accA); \
    }                                                                        \
    ACC = (accA + accB) + (accC + accD); }

  SEGP(ev0, b0v, c0, a0);
  SEGP(ev1, b1v, c1, a1);
  SEGP(ev2, b2v, c2, a2);
  SEGP(ev3, b3v, c3, a3);
#undef SEGP

  // stage aggregates into wave-private LDS slots (sred[r][w*64+lane])
  sred[0][t] = a0; sred[1][t] = a1; sred[2][t] = a2; sred[3][t] = a3;
  __syncthreads();   // wsh ready (stage is wave-private, sync harmless)

  // projection: b0..b3 via uniform LDS broadcast reads (no readlane)
  int rows = NPG_ - dt * TROWS_; if (rows > TROWS_) rows = TROWS_;
  const f2v* wp = (const f2v*)wsh;
  const int wb = w * 64;
  f2v A0 = {0.f,0.f}, A1 = {0.f,0.f}, A2 = {0.f,0.f}, A3 = {0.f,0.f};
  #pragma unroll 1
  for (int k = 0; k < 64; ++k){
    f2v wv = wp[k * 64 + lane];
    float b0 = sred[0][wb + k];
    float b1 = sred[1][wb + k];
    float b2 = sred[2][wb + k];
    float b3 = sred[3][wb + k];
    A0.x = fmaf(b0, wv.x, A0.x); A0.y = fmaf(b0, wv.y, A0.y);
    A1.x = fmaf(b1, wv.x, A1.x); A1.y = fmaf(b1, wv.y, A1.y);
    A2.x = fmaf(b2, wv.x, A2.x); A2.y = fmaf(b2, wv.y, A2.y);
    A3.x = fmaf(b3, wv.x, A3.x); A3.y = fmaf(b3, wv.y, A3.y);
  }
  float s0 = 0.f, q0 = 0.f, s1 = 0.f, q1 = 0.f;
  #pragma unroll
  for (int r = 0; r < 4; ++r){
    int lr = w * 4 + r;
    if (lr < rows){
      f2v A = (r == 0) ? A0 : (r == 1) ? A1 : (r == 2) ? A2 : A3;
      int cr = (r == 0) ? c0 : (r == 1) ? c1 : (r == 2) ? c2 : c3;
      float ri = rsqrtf((float)(cr < 1 ? 1 : cr));
      int node = g * NPG_ + dt * TROWS_ + lr;
      A.x *= ri; A.y *= ri;
      __builtin_nontemporal_store(A, (f2v*)&h1[(size_t)node * 128 + 2 * lane]);
      s0 += A.x; q0 = fmaf(A.x, A.x, q0);
      s1 += A.y; q1 = fmaf(A.y, A.y, q1);
    }
  }
  __syncthreads();   // all waves done reading stage before overwrite
  sred[0][t] = s0; sred[1][t] = q0; sred[2][t] = s1; sred[3][t] = q1;
  __syncthreads();
  if (t < 64){
    float S0 = 0.f, Q0 = 0.f, S1 = 0.f, Q1 = 0.f;
    #pragma unroll
    for (int ww = 0; ww < 8; ++ww){
      S0 += sred[0][t + 64*ww]; Q0 += sred[1][t + 64*ww];
      S1 += sred[2][t + 64*ww]; Q1 += sred[3][t + 64*ww];
    }
    atomicAdd(&gsum[g * 128 + 2*t],     S0);
    atomicAdd(&gsq [g * 128 + 2*t],     Q0);
    atomicAdd(&gsum[g * 128 + 2*t + 1], S1);
    atomicAdd(&gsq [g * 128 + 2*t + 1], Q1);
  }
}

__global__ void finalize1(const float* __restrict__ gsum, const float* __restrict__ gsq,
                          const float* __restrict__ gamma, const float* __restrict__ beta,
                          const float* __restrict__ alpha, float* __restrict__ mul, float* __restrict__ add){
  int i = threadIdx.x;            // 1024
  int c = i & 127;
  const float invn = 1.0f / (float)NPG_;
  float m = gsum[i] * invn;
  float a = alpha[c];
  float var = gsq[i] * invn - 2.f * a * m * m + a * a * m * m;
  float mu = gamma[c] * rsqrtf(var + 1e-5f);
  mul[i] = mu;
  add[i] = beta[c] - mu * a * m;
}

// ---------------- fused: normalize h1 + sort keys + project to h2p ----------------
__global__ __launch_bounds__(256, 4)
void normproj(const float* __restrict__ h1,
              const float* __restrict__ mul, const float* __restrict__ add,
              const float* __restrict__ W2,
              unsigned long long* __restrict__ keys, float* __restrict__ h2p){
  __shared__ float w2s[128 * 32];  // 16 KB
  __shared__ float ys[4][128];     // 2 KB, wave-private rows
  int t = threadIdx.x;
  for (int i = t; i < 128 * 32; i += 256) w2s[i] = W2[i];
  __syncthreads();

  int g     = blockIdx.x & 7;
  int wslot = (blockIdx.x >> 3) * 4 + (t >> 6);   // 0..1023
  int w     = t >> 6;
  int lane  = t & 63;
  int c     = lane & 31, hh = lane >> 5;
  int kb    = hh * 64;

  float m0 = mul[g * 128 + lane],      aa0 = add[g * 128 + lane];
  float m1 = mul[g * 128 + 64 + lane], aa1 = add[g * 128 + 64 + lane];

  int nv = (NPG_ - wslot + 1023) / 1024;

  int v0 = g * NPG_ + wslot;
  float x0 = __builtin_nontemporal_load(&h1[(size_t)v0 * 128 + lane]);
  float x1 = __builtin_nontemporal_load(&h1[(size_t)v0 * 128 + 64 + lane]);

  for (int i = 0; i < nv; ++i){
    int v = g * NPG_ + wslot + i * 1024;
    float cur0 = x0, cur1 = x1;
    if (i + 1 < nv){
      int vn = v + 1024;
      x0 = __builtin_nontemporal_load(&h1[(size_t)vn * 128 + lane]);
      x1 = __builtin_nontemporal_load(&h1[(size_t)vn * 128 + 64 + lane]);
    }
    float y0 = lrelu(fmaf(m0, cur0, aa0));
    float y1 = lrelu(fmaf(m1, cur1, aa1));
    ys[w][lane]      = y0;
    ys[w][64 + lane] = y1;
    float mx = fmaxf(y0, y1);
    for (int o = 1; o < 64; o <<= 1) mx = fmaxf(mx, __shfl_xor(mx, o));
    if (lane == 0){
      unsigned u = __float_as_uint(mx);
      u ^= (u >> 31) ? 0xFFFFFFFFu : 0x80000000u;
      int nloc = v - g * NPG_;
      keys[(size_t)g * NKEY_ + nloc] = ((unsigned long long)(~u) << 32) | (unsigned)nloc;
    }
    float ac0 = 0.f, ac1 = 0.f, ac2 = 0.f, ac3 = 0.f;
    #pragma unroll
    for (int kk = 0; kk < 16; ++kk){
      ac0 = fmaf(ys[w][kb + kk],      w2s[(kb + kk) * 32 + c],      ac0);
      ac1 = fmaf(ys[w][kb + kk + 16], w2s[(kb + kk + 16) * 32 + c], ac1);
      ac2 = fmaf(ys[w][kb + kk + 32], w2s[(kb + kk + 32) * 32 + c], ac2);
      ac3 = fmaf(ys[w][kb + kk + 48], w2s[(kb + kk + 48) * 32 + c], ac3);
    }
    float acc = (ac0 + ac1) + (ac2 + ac3);
    acc += __shfl_xor(acc, 32);
    if (hh == 0) h2p[(size_t)v * 32 + c] = acc;
  }
}

// ---------------- top-k selection (2-stage bitonic) ----------------
__global__ void topk_s1(const unsigned long long* __restrict__ keys, unsigned long long* __restrict__ cand){
  __shared__ unsigned long long s[2048];
  int b = blockIdx.x >> 3, ch = blockIdx.x & 7;
  int t = threadIdx.x;            // 256
  for (int i = t; i < 2048; i += 256) s[i] = keys[(size_t)b * NKEY_ + (size_t)ch * 2048 + i];
  for (int k2 = 2; k2 <= 2048; k2 <<= 1){
    for (int j = k2 >> 1; j > 0; j >>= 1){
      __syncthreads();
      for (int i = t; i < 2048; i += 256){
        int p = i ^ j;
        if (p > i){
          unsigned long long A = s[i], C = s[p];
          bool up = ((i & k2) == 0);
          if ((A > C) == up){ s[i] = C; s[p] = A; }
        }
      }
    }
  }
  __syncthreads();
  if (t < 64) cand[(size_t)b * 512 + (size_t)ch * 64 + t] = s[t];
}

__global__ void topk_s2(const unsigned long long* __restrict__ cand, int* __restrict__ topidx){
  __shared__ unsigned long long s[512];
  int b = blockIdx.x;
  int t = threadIdx.x;            // 256
  for (int i = t; i < 512; i += 256) s[i] = cand[(size_t)b * 512 + i];
  for (int k2 = 2; k2 <= 512; k2 <<= 1){
    for (int j = k2 >> 1; j > 0; j >>= 1){
      __syncthreads();
      for (int i = t; i < 512; i += 256){
        int p = i ^ j;
        if (p > i){
          unsigned long long A = s[i], C = s[p];
          bool up = ((i & k2) == 0);
          if ((A > C) == up){ s[i] = C; s[p] = A; }
        }
      }
    }
  }
  __syncthreads();
  if (t < 64) topidx[b * 64 + t] = (int)(s[t] & 0xFFFFFFFFull);
}

__global__ void emit1(const float* __restrict__ h1, const int* __restrict__ topidx,
                      const float* __restrict__ mul, const float* __restrict__ add,
                      float* __restrict__ out){
  __shared__ float s[128];
  int b = blockIdx.x >> 6, k = blockIdx.x & 63;
  int t = threadIdx.x;            // 128
  int nloc = topidx[b * 64 + k];
  float raw = h1[((size_t)b * NPG_ + nloc) * 128 + t];
  s[t] = lrelu(fmaf(mul[b * 128 + t], raw, add[b * 128 + t]));
  for (int k2 = 2; k2 <= 128; k2 <<= 1){
    for (int j = k2 >> 1; j > 0; j >>= 1){
      __syncthreads();
      int p = t ^ j;
      if (p > t){
        float A = s[t], C = s[p];
        bool up = ((t & k2) == 0);
        if ((A > C) == up){ s[t] = C; s[p] = A; }
      }
    }
  }
  __syncthreads();
  out[(size_t)b * OUT_ROW + (size_t)k * 128 + t] = lrelu(s[t]);
}

// ---------------- layer 2: per-row-segment SpMM on h2p + stats ----------------
// All 4 segments' bounds + batch loads hoisted (4 vmem chains in flight).
__global__ __launch_bounds__(512, 4)
void spmm2_tile(const int* __restrict__ boff, const i2v* __restrict__ bkt,
                const float* __restrict__ h2p, float* __restrict__ h2c,
                float* __restrict__ gsum, float* __restrict__ gsq){
  __shared__ float sred[2][512];
  int t = threadIdx.x;
  int w = t >> 6, lane = t & 63;
  int c = lane & 31, h = lane >> 5;
  int g = blockIdx.x & 7, dt = blockIdx.x >> 3;

  int wk = ((g * NT_DST + dt) * 32 + w * 4) * NT_SRC;
  const float* hg = h2p + (size_t)g * NPG_ * 32;
  int rows = NPG_ - dt * TROWS_; if (rows > TROWS_) rows = TROWS_;

  // hoisted segment bounds
  int b0v = boff[wk];
  int b1v = boff[wk + NT_SRC];
  int b2v = boff[wk + 2 * NT_SRC];
  int b3v = boff[wk + 3 * NT_SRC];
  int nx  = wk + 4 * NT_SRC;
  int b4v = (nx < NBKT) ? boff[nx] : TOTAL_E_;
  int c0 = b1v - b0v, c1 = b2v - b1v, c2 = b3v - b2v, c3 = b4v - b3v;

  // hoisted batch loads
  i2v ev0 = {0,0}, ev1 = {0,0}, ev2 = {0,0}, ev3 = {0,0};
  if (lane < (c0 < 64 ? c0 : 64)) ev0 = bkt[b0v + lane];
  if (lane < (c1 < 64 ? c1 : 64)) ev1 = bkt[b1v + lane];
  if (lane < (c2 < 64 ? c2 : 64)) ev2 = bkt[b2v + lane];
  if (lane < (c3 < 64 ? c3 : 64)) ev3 = bkt[b3v + lane];

  float A0, A1, A2, A3;

#define SEGP2(EV, BASE, CNT, ACC) {                                          \
    int m_ = (CNT) < 64 ? (CNT) : 64;                                        \
    float ac0 = 0.f, ac1 = 0.f;                                              \
    int j = 0;                                                               \
    for (; j + 4 <= m_; j += 4){                                             \
      int   pA0 = rlanei(EV.x, j+0), pB0 = rlanei(EV.x, j+1);                \
      int   pA1 = rlanei(EV.x, j+2), pB1 = rlanei(EV.x, j+3);                \
      float qA0 = rlanef(__int_as_float(EV.y), j+0), qB0 = rlanef(__int_as_float(EV.y), j+1); \
      float qA1 = rlanef(__int_as_float(EV.y), j+2), qB1 = rlanef(__int_as_float(EV.y), j+3); \
      int   p0 = h ? pB0 : pA0;  float q0 = h ? qB0 : qA0;                   \
      int   p1 = h ? pB1 : pA1;  float q1 = h ? qB1 : qA1;                   \
      float f0 = hg[(size_t)p0 * 32 + c];                                    \
      float f1 = hg[(size_t)p1 * 32 + c];                                    \
      ac0 = fmaf(q0, f0, ac0); ac1 = fmaf(q1, f1, ac1);                      \
    }                                                                        \
    for (; j + 2 <= m_; j += 2){                                             \
      int   pA = rlanei(EV.x, j), pB = rlanei(EV.x, j+1);                    \
      float qA = rlanef(__int_as_float(EV.y), j), qB = rlanef(__int_as_float(EV.y), j+1); \
      int   p = h ? pB : pA;  float q = h ? qB : qA;                         \
      ac0 = fmaf(q, hg[(size_t)p * 32 + c], ac0);                            \
    }                                                                        \
    if (j < m_){                                                             \
      int   p = rlanei(EV.x, j);                                             \
      float q = h ? 0.f : rlanef(__int_as_float(EV.y), j);                   \
      ac0 = fmaf(q, hg[(size_t)p * 32 + c], ac0);                            \
    }                                                                        \
    for (int e2 = (BASE) + 64; e2 < (BASE) + (CNT); ++e2){                   \
      i2v ed = bkt[e2];                                                      \
      float q = h ? 0.f : __int_as_float(ed.y);                              \
      ac0 = fmaf(q, hg[(size_t)ed.x * 32 + c], ac0);                         \
    }                                                                        \
    float acc_ = ac0 + ac1;                                                  \
    acc_ += __shfl_xor(acc_, 32);                                            \
    ACC = acc_; }

  SEGP2(ev0, b0v, c0, A0);
  SEGP2(ev1, b1v, c1, A1);
  SEGP2(ev2, b2v, c2, A2);
  SEGP2(ev3, b3v, c3, A3);
#undef SEGP2

  float ssum = 0.f, ssq = 0.f;
  #pragma unroll
  for (int r = 0; r < 4; ++r){
    float acc = (r == 0) ? A0 : (r == 1) ? A1 : (r == 2) ? A2 : A3;
    int   cr  = (r == 0) ? c0 : (r == 1) ? c1 : (r == 2) ? c2 : c3;
    int lr = w * 4 + r;
    if (lr < rows && h == 0){
      float ri = rsqrtf((float)(cr < 1 ? 1 : cr));
      float val = acc * ri;
      int node = g * NPG_ + dt * TROWS_ + lr;
      __builtin_nontemporal_store(val, &h2c[(size_t)node * 32 + c]);
      ssum += val; ssq = fmaf(val, val, ssq);
    }
  }

  __syncthreads();
  sred[0][t] = ssum; sred[1][t] = ssq;
  __syncthreads();
  if (t < 32){
    float S = 0.f, Q = 0.f;
    #pragma unroll
    for (int k = 0; k < 16; ++k){
      S += sred[0][t + 32 * k];
      Q += sred[1][t + 32 * k];
    }
    atomicAdd(&gsum[g * 32 + t], S);
    atomicAdd(&gsq [g * 32 + t], Q);
  }
}

__global__ void finalize2(const float* __restrict__ gsum, const float* __restrict__ gsq,
                          const float* __restrict__ gamma, const float* __restrict__ beta,
                          const float* __restrict__ alpha, float* __restrict__ mul, float* __restrict__ add){
  int i = threadIdx.x;            // 256
  int c = i & 31;
  const float invn = 1.0f / (float)NPG_;
  float m = gsum[i] * invn;
  float a = alpha[c];
  float var = gsq[i] * invn - 2.f * a * m * m + a * a * m * m;
  float mu = gamma[c] * rsqrtf(var + 1e-5f);
  mul[i] = mu;
  add[i] = beta[c] - mu * a * m;
}

__global__ void norm2(float* __restrict__ h, const float* __restrict__ mul, const float* __restrict__ add,
                      unsigned long long* __restrict__ keys){
  int tid  = blockIdx.x * 256 + threadIdx.x;
  int node = tid >> 5;
  int sl   = tid & 31;
  if (node >= TOTAL_N_) return;
  int b = node / NPG_;
  int nloc = node - b * NPG_;
  float v = h[(size_t)node * 32 + sl];
  v = lrelu(fmaf(mul[b * 32 + sl], v, add[b * 32 + sl]));
  h[(size_t)node * 32 + sl] = v;
  float m = v;
  for (int o = 1; o < 32; o <<= 1) m = fmaxf(m, __shfl_xor(m, o));
  if (sl == 0){
    unsigned u = __float_as_uint(m);
    u ^= (u >> 31) ? 0xFFFFFFFFu : 0x80000000u;
    keys[(size_t)b * NKEY_ + nloc] = ((unsigned long long)(~u) << 32) | (unsigned)nloc;
  }
}

__global__ void emit2(const float* __restrict__ h2, const int* __restrict__ topidx, float* __restrict__ out){
  int b = blockIdx.x >> 6, k = blockIdx.x & 63;
  int lane = threadIdx.x;         // 32
  int nloc = topidx[b * 64 + k];
  float v = h2[((size_t)b * NPG_ + nloc) * 32 + lane];
  for (int k2 = 2; k2 <= 32; k2 <<= 1){
    for (int j = k2 >> 1; j > 0; j >>= 1){
      float o = __shfl_xor(v, j);
      bool up    = ((lane & k2) == 0);
      bool lower = ((lane & j) == 0);
      v = (up == lower) ? fminf(v, o) : fmaxf(v, o);
    }
  }
  out[(size_t)b * OUT_ROW + 8192 + (size_t)k * 32 + lane] = lrelu(v);
}

__global__ void sentinel_kernel(float* out){
  int i = blockIdx.x * 256 + threadIdx.x;
  if (i < B_ * OUT_ROW) out[i] = -777.0f;
}

extern "C" void kernel_launch(void* const* d_in, const int* in_sizes, int n_in,
                              void* d_out, int out_size, void* d_ws, size_t ws_size,
                              hipStream_t stream){
  const float* feat   = (const float*)d_in[0];
  const float* ew     = (const float*)d_in[1];
  const float* W1     = (const float*)d_in[2];
  const float* W2     = (const float*)d_in[3];
  const float* gamma1 = (const float*)d_in[4];
  const float* beta1  = (const float*)d_in[5];
  const float* alpha1 = (const float*)d_in[6];
  const float* gamma2 = (const float*)d_in[7];
  const float* beta2  = (const float*)d_in[8];
  const float* alpha2 = (const float*)d_in[9];
  const int*   esrc   = (const int*)d_in[10];
  const int*   edst   = (const int*)d_in[11];
  float* out = (float*)d_out;

  char* ws = (char*)d_ws;
  auto alloc = [&](size_t bytes) -> char* {
    char* p = ws;
    ws += (bytes + 255) & ~(size_t)255;
    return p;
  };

  // zeroed region (must stay first & contiguous)
  float* gsum1   = (float*)alloc(1024 * 4);
  float* gsq1    = (float*)alloc(1024 * 4);
  float* gsum2   = (float*)alloc(256 * 4);
  float* gsq2    = (float*)alloc(256 * 4);
  size_t zero_bytes = (size_t)(ws - (char*)d_ws);

  float* rsq_out = (float*)alloc((size_t)TOTAL_N_ * 4);
  unsigned short* out_part = (unsigned short*)alloc((size_t)NHB_ * NPG_ * 2);   // 6.4 MB
  unsigned short* bkt_part = (unsigned short*)alloc((size_t)NHB_ * LBKT_ * 2);  // 12.8 MB
  unsigned short* lrank = (unsigned short*)alloc((size_t)TOTAL_E_ * 2);         // 3.2 MB
  int*   bcnt    = (int*)  alloc((size_t)NBKT * 4);
  int*   boff    = (int*)  alloc((size_t)NBKT * 4);
  int*   bsum    = (int*)  alloc(1024 * 4);
  float* mul1    = (float*)alloc(1024 * 4);
  float* add1    = (float*)alloc(1024 * 4);
  float* mul2    = (float*)alloc(256 * 4);
  float* add2    = (float*)alloc(256 * 4);
  int*   topidx1 = (int*)  alloc(512 * 4);
  int*   topidx2 = (int*)  alloc(512 * 4);
  unsigned long long* cand = (unsigned long long*)alloc((size_t)B_ * 512 * 8);
  unsigned long long* keys = (unsigned long long*)alloc((size_t)B_ * NKEY_ * 8);
  i2v*   bkt     = (i2v*)  alloc((size_t)TOTAL_E_ * 8);
  float* h2p     = (float*)alloc((size_t)TOTAL_N_ * 32 * 4);
  float* h2c     = (float*)alloc((size_t)TOTAL_N_ * 32 * 4);
  float* h1      = (float*)alloc((size_t)TOTAL_N_ * 128 * 4);

  size_t need = (size_t)(ws - (char*)d_ws);
  if (need > ws_size){
    sentinel_kernel<<<(B_ * OUT_ROW + 255) / 256, 256, 0, stream>>>(out);
    return;
  }

  hipMemsetAsync(d_ws, 0, zero_bytes, stream);
  hipMemsetAsync(keys, 0xFF, (size_t)B_ * NKEY_ * 8, stream);

  hist_priv        <<<NHB_, 1024, 0, stream>>>(esrc, edst, out_part, bkt_part, lrank);
  hist_reduce_nodes<<<NB_SCAN, 256, 0, stream>>>(out_part, rsq_out);
  hist_reduce_bkt  <<<NB_BSCAN, 256, 0, stream>>>(bkt_part, bcnt);
  scan_blocks      <<<NB_BSCAN, 256, 0, stream>>>(bcnt, boff, bsum, NBKT);
  scan_sums        <<<1, 1024, 0, stream>>>(bsum, NB_BSCAN);
  scan_add         <<<NB_BSCAN, 256, 0, stream>>>(boff, bsum, NBKT);
  bfill2           <<<8 * BPG_, 256, 0, stream>>>(esrc, edst, ew, rsq_out, lrank,
                                                  bkt_part, boff, bkt);

  // layer 1
  spmm1_tile <<<NT_DST * 8, 512, 0, stream>>>(boff, bkt, feat, W1, h1, gsum1, gsq1);
  finalize1  <<<1, 1024, 0, stream>>>(gsum1, gsq1, gamma1, beta1, alpha1, mul1, add1);
  normproj   <<<2048, 256, 0, stream>>>(h1, mul1, add1, W2, keys, h2p);
  topk_s1    <<<B_ * 8, 256, 0, stream>>>(keys, cand);
  topk_s2    <<<B_, 256, 0, stream>>>(cand, topidx1);
  emit1      <<<B_ * 64, 128, 0, stream>>>(h1, topidx1, mul1, add1, out);

  // layer 2
  spmm2_tile <<<NT_DST * 8, 512, 0, stream>>>(boff, bkt, h2p, h2c, gsum2, gsq2);
  finalize2  <<<1, 256, 0, stream>>>(gsum2, gsq2, gamma2, beta2, alpha2, mul2, add2);
  norm2      <<<TOTAL_N_ * 32 / 256, 256, 0, stream>>>(h2c, mul2, add2, keys);
  topk_s1    <<<B_ * 8, 256, 0, stream>>>(keys, cand);
  topk_s2    <<<B_, 256, 0, stream>>>(cand, topidx2);
  emit2      <<<B_ * 64, 32, 0, stream>>>(h2c, topidx2, out);
}